// Round 6
// baseline (235.382 us; speedup 1.0000x reference)
//
#include <hip/hip_runtime.h>
#include <hip/hip_bf16.h>

using bf16 = __hip_bfloat16;

#define F 64
#define HG 128
#define HL 128
#define AVG_LOG_INV 0.45511961331341866f  // 1/log(9)
#define BSH 4            // 16 nodes per bucket
#define BNODES 16
#define BCAP 512         // per-bucket record capacity (mean 256, +16 sigma)
#define BTILE 32768      // edges per partition block
#define NBMAX 3200       // LDS hist array size (>= NB)
#define NBTMAX 32        // max partition blocks (E <= 32*32768 = 1M)

typedef short short8 __attribute__((ext_vector_type(8)));
typedef float floatx4 __attribute__((ext_vector_type(4)));

__device__ __forceinline__ float b2f(bf16 v) { return __bfloat162float(v); }
__device__ __forceinline__ bf16 f2b(float v) { return __float2bfloat16(v); }
__device__ __forceinline__ short f2bs(float v) { bf16 h = f2b(v); return *(short*)&h; }

__device__ __forceinline__ unsigned packbf2(float x, float y) {
    bf16 a = f2b(x), b = f2b(y);
    unsigned short ua = *(unsigned short*)&a, ub = *(unsigned short*)&b;
    return ((unsigned)ub << 16) | (unsigned)ua;
}

__device__ __forceinline__ float wave_sum(float v) {
    #pragma unroll
    for (int m = 32; m > 0; m >>= 1) v += __shfl_xor(v, m);
    return v;
}

// Fused: [init gfeat/gcnt/uc] + edge partition (blocks < NBT) + AB MFMA staging
// (blocks >= NBT). Partition is block-local CSR: block p sorts its BTILE edges
// by bucket into gout[p*BTILE..], writes per-bucket offsets ofs[p][b].
__global__ __launch_bounds__(512) void k_prep(
    const float* __restrict__ x, const float* __restrict__ W_pre,
    bf16* __restrict__ AB, int N,
    const int* __restrict__ ei, const float* __restrict__ ea,
    int* __restrict__ ofs, int2* __restrict__ gout, int E,
    float* __restrict__ gfeat, int* __restrict__ gcnt,
    int NB, int GF, int G, int NBT,
    const float* __restrict__ W_edge, const float* __restrict__ b_edge,
    const float* __restrict__ b_pre, float* __restrict__ uc) {
    __shared__ __align__(16) char smem[2 * NBMAX * 4];   // 25.6KB (>=18.4KB wt)
    int t = threadIdx.x;  // 512
    int gtid = blockIdx.x * 512 + t;
    int gstr = gridDim.x * 512;
    for (int i = gtid; i < GF; i += gstr) gfeat[i] = 0.f;
    for (int i = gtid; i < G; i += gstr) gcnt[i] = 0;

    if (blockIdx.x < NBT) {
        // ---------------- partition role ----------------
        int* hist = (int*)smem;          // NBMAX: counts -> exclusive offsets
        int* aux  = hist + NBMAX;        // NBMAX: scan temp -> rank counters
        int p = blockIdx.x;
        for (int i = t; i < NB; i += 512) hist[i] = 0;
        __syncthreads();
        int base = p * BTILE;
        int lim = E - base; if (lim > BTILE) lim = BTILE;
        int nq = lim >> 2;
        const int4* dst4 = (const int4*)(ei + E + base);
        for (int q = t; q < nq; q += 512) {
            int4 d = dst4[q];
            atomicAdd(&hist[d.x >> BSH], 1);
            atomicAdd(&hist[d.y >> BSH], 1);
            atomicAdd(&hist[d.z >> BSH], 1);
            atomicAdd(&hist[d.w >> BSH], 1);
        }
        for (int i = (nq << 2) + t; i < lim; i += 512)
            atomicAdd(&hist[ei[E + base + i] >> BSH], 1);
        __syncthreads();
        // exclusive scan over NB buckets: each thread owns 8 consecutive
        int b0 = t * 8;
        int c[8]; int tot = 0;
        #pragma unroll
        for (int j = 0; j < 8; j++) {
            c[j] = (b0 + j < NB) ? hist[b0 + j] : 0;
            tot += c[j];
        }
        aux[t] = tot;
        __syncthreads();
        for (int d = 1; d < 512; d <<= 1) {
            int v = (t >= d) ? aux[t - d] : 0;
            __syncthreads();
            aux[t] += v;
            __syncthreads();
        }
        int run = aux[t] - tot;  // exclusive prefix for this thread's group
        __syncthreads();
        size_t orow = (size_t)p * (NB + 1);
        #pragma unroll
        for (int j = 0; j < 8; j++) {
            if (b0 + j < NB) {
                hist[b0 + j] = run;
                ofs[orow + b0 + j] = run;
                run += c[j];
            }
        }
        if (t == 0) ofs[orow + NB] = lim;
        for (int i = t; i < NB; i += 512) aux[i] = 0;  // rank counters
        __syncthreads();
        // pass 2: re-read edges, scatter into block-local segment (256KB window)
        const int4* src4 = (const int4*)(ei + base);
        const float4* ea4 = (const float4*)(ea + base);
        int2* seg = gout + (size_t)p * BTILE;
        for (int q = t; q < nq; q += 512) {
            int4 s = src4[q], d = dst4[q];
            float4 v = ea4[q];
            int bb, pos;
            bb = d.x >> BSH; pos = hist[bb] + atomicAdd(&aux[bb], 1);
            seg[pos] = make_int2((d.x << 16) | s.x, __float_as_int(v.x));
            bb = d.y >> BSH; pos = hist[bb] + atomicAdd(&aux[bb], 1);
            seg[pos] = make_int2((d.y << 16) | s.y, __float_as_int(v.y));
            bb = d.z >> BSH; pos = hist[bb] + atomicAdd(&aux[bb], 1);
            seg[pos] = make_int2((d.z << 16) | s.z, __float_as_int(v.z));
            bb = d.w >> BSH; pos = hist[bb] + atomicAdd(&aux[bb], 1);
            seg[pos] = make_int2((d.w << 16) | s.w, __float_as_int(v.w));
        }
        for (int i = (nq << 2) + t; i < lim; i += 512) {
            int s = ei[base + i], d = ei[E + base + i];
            int bb = d >> BSH;
            int pos = hist[bb] + atomicAdd(&aux[bb], 1);
            seg[pos] = make_int2((d << 16) | s, __float_as_int(ea[base + i]));
        }
    } else {
        // ---------------- AB MFMA role ----------------
        if (blockIdx.x == NBT && t < 64) {
            int f = t;
            float u = 0.f, c2 = b_pre[f];
            for (int k = 0; k < 64; k++) {
                float w3 = W_pre[(128 + k) * 64 + f];
                u += W_edge[k] * w3;
                c2 += b_edge[k] * w3;
            }
            uc[f] = u; uc[64 + f] = c2;
        }
        unsigned short* wt = (unsigned short*)smem;  // wt[m][k], 128x72
        for (int idx = t; idx < 8192; idx += 512) {
            int k = idx >> 7, m = idx & 127;
            float v = W_pre[((m & 64) + k) * 64 + (m & 63)];
            wt[m * 72 + k] = (unsigned short)f2bs(v);
        }
        __syncthreads();

        int lane = t & 63;
        int row = lane & 15, quad = lane >> 4;
        int w = (blockIdx.x - NBT) * 8 + (t >> 6);
        int nwaves = (gridDim.x - NBT) * 8;
        int ntiles = (N + 15) >> 4;

        for (int tile = w; tile < ntiles; tile += nwaves) {
            int m0 = tile << 4;
            int node_a = m0 + row; if (node_a >= N) node_a = N - 1;
            short8 a[2];
            #pragma unroll
            for (int h = 0; h < 2; h++) {
                const float* xp = x + (size_t)node_a * 64 + h * 32 + quad * 8;
                floatx4 v0 = *(const floatx4*)xp;
                floatx4 v1 = *(const floatx4*)(xp + 4);
                #pragma unroll
                for (int j = 0; j < 4; j++) { a[h][j] = f2bs(v0[j]); a[h][4 + j] = f2bs(v1[j]); }
            }
            #pragma unroll
            for (int tt = 0; tt < 8; tt++) {
                int fbase = tt * 16;
                floatx4 c = {0.f, 0.f, 0.f, 0.f};
                #pragma unroll
                for (int h = 0; h < 2; h++) {
                    short8 bfr = *(const short8*)(wt + (fbase + row) * 72 + h * 32 + quad * 8);
                    c = __builtin_amdgcn_mfma_f32_16x16x32_bf16(a[h], bfr, c, 0, 0, 0);
                }
                #pragma unroll
                for (int r = 0; r < 4; r++) {
                    int node = m0 + quad * 4 + r;
                    if (node < N) AB[(size_t)node * 128 + fbase + row] = f2b(c[r]);
                }
            }
        }
    }
}

// one block (256 thr, 4 waves) per bucket (16 nodes). Setup: 25 CSR runs
// (one ofs pair per lane, 32-lane shfl scan, depth-5 binary search assembly),
// LDS counting-sort, dual-node LDS-broadcast gather, fused per-graph segment
// reduce (193 cols: 128 stats + 64 x + cnt).
__global__ __launch_bounds__(256) void k_edge(
    const bf16* __restrict__ AB, const int2* __restrict__ gout,
    const int* __restrict__ ofs, const float* __restrict__ uc,
    const int* __restrict__ batch, const float* __restrict__ x,
    float* __restrict__ gfeat, int* __restrict__ gcnt,
    int N, int NB, int NBT) {
    __shared__ int2 recs[BCAP], sortd[BCAP];
    __shared__ int ncnt[BNODES], nofs[BNODES], nrank[BNODES];
    __shared__ int gid[BNODES];
    __shared__ unsigned lstat[BNODES][128];   // packed bf16 pairs: [mean|mn|mx|sd]
    __shared__ float lamp[BNODES], liamp[BNODES];
    __shared__ int runlo[NBTMAX], runpre[NBTMAX];
    __shared__ int etot_s;
    int t = threadIdx.x;  // 256
    int b = blockIdx.x;
    int nn = N - b * BNODES; if (nn > BNODES) nn = BNODES;

    // ---- setup: lanes 0..31 each own one partition run; 32-lane shfl scan
    if (t < 64) {
        int l = t;
        int lo0 = 0, len0 = 0;
        if (l < NBT) {
            lo0 = ofs[(size_t)l * (NB + 1) + b];
            len0 = ofs[(size_t)l * (NB + 1) + b + 1] - lo0;
        }
        if (l < NBTMAX) runlo[l] = lo0;
        int inc = len0;
        #pragma unroll
        for (int m = 1; m < 32; m <<= 1) { int u = __shfl_up(inc, m); if ((l & 31) >= m) inc += u; }
        if (l < NBTMAX) runpre[l] = inc - len0;
        if (l == 31) etot_s = inc;
    } else if (t < 64 + BNODES) {
        int i = t - 64;  // i < BNODES
        ncnt[i] = 0; nrank[i] = 0;
        if (i < nn) gid[i] = batch[b * BNODES + i];
    }
    __syncthreads();

    int ecnt = etot_s; if (ecnt > BCAP) ecnt = BCAP;
    for (int i = t; i < ecnt; i += 256) {
        int lo2 = 0, hi2 = NBTMAX;  // largest p with runpre[p] <= i
        while (hi2 - lo2 > 1) {
            int mid = (lo2 + hi2) >> 1;
            if (runpre[mid] <= i) lo2 = mid; else hi2 = mid;
        }
        int2 r = gout[(size_t)lo2 * BTILE + runlo[lo2] + (i - runpre[lo2])];
        recs[i] = r;
        atomicAdd(&ncnt[((unsigned)r.x >> 16) & (BNODES - 1)], 1);
    }
    __syncthreads();
    if (t < BNODES) {  // exclusive scan over node counts
        int v = ncnt[t], inc = v;
        #pragma unroll
        for (int m = 1; m < BNODES; m <<= 1) { int u = __shfl_up(inc, m); if (t >= m) inc += u; }
        nofs[t] = inc - v;
    }
    __syncthreads();
    for (int i = t; i < ecnt; i += 256) {
        int2 r = recs[i];
        int nl = ((unsigned)r.x >> 16) & (BNODES - 1);
        int k = atomicAdd(&nrank[nl], 1);
        sortd[nofs[nl] + k] = r;
    }
    __syncthreads();

    int lane = t & 63, w = t >> 6;  // 4 waves
    int half = lane & 31, hi32 = lane >> 5;
    float2 u2 = *(const float2*)(uc + 2 * half);
    float2 c2 = *(const float2*)(uc + 64 + 2 * half);

    // dual-node gather: wave w handles nodes (nl, nl+4) concurrently
    for (int nl = w; nl < nn; nl += 8) {
        int nlA = nl, nlB = nl + 4;
        bool hasB = (nlB < nn);
        int nA = b * BNODES + nlA;
        int nB = b * BNODES + (hasB ? nlB : nlA);
        int loA = nofs[nlA], cntA = ncnt[nlA];
        int loB = hasB ? nofs[nlB] : 0, cntB = hasB ? ncnt[nlB] : 0;

        unsigned apA = *(const unsigned*)(AB + (size_t)nA * 128 + 2 * half);
        unsigned apB = *(const unsigned*)(AB + (size_t)nB * 128 + 2 * half);
        float acxA = __uint_as_float(apA << 16) + c2.x;
        float acyA = __uint_as_float(apA & 0xffff0000u) + c2.y;
        float acxB = __uint_as_float(apB << 16) + c2.x;
        float acyB = __uint_as_float(apB & 0xffff0000u) + c2.y;

        float sxA = 0.f, syA = 0.f, qxA = 0.f, qyA = 0.f;
        float mnxA = 3.4e38f, mnyA = 3.4e38f, mxxA = -3.4e38f, mxyA = -3.4e38f;
        float sxB = 0.f, syB = 0.f, qxB = 0.f, qyB = 0.f;
        float mnxB = 3.4e38f, mnyB = 3.4e38f, mxxB = -3.4e38f, mxyB = -3.4e38f;

        auto gaddr = [&](int sn) {
            return (const unsigned*)(AB + (size_t)sn * 128 + 64 + 2 * half);
        };

        // hi32=0 lanes take even edge indices, hi32=1 odd
        for (int i = hi32; (i < cntA) || (i < cntB); i += 8) {
            unsigned bpA[4], bpB[4];
            #pragma unroll
            for (int j = 0; j < 4; j++) {
                int idx = i + 2 * j;
                int e = loA + (idx < cntA ? idx : 0);
                bpA[j] = *gaddr(sortd[e].x & 0xFFFF);   // LDS broadcast -> gather
            }
            #pragma unroll
            for (int j = 0; j < 4; j++) {
                int idx = i + 2 * j;
                int e = loB + (idx < cntB ? idx : 0);
                bpB[j] = *gaddr(sortd[e].x & 0xFFFF);
            }
            #pragma unroll
            for (int j = 0; j < 4; j++) {
                int idx = i + 2 * j;
                if (idx < cntA) {
                    float eav = __int_as_float(sortd[loA + idx].y);
                    float bx = __uint_as_float(bpA[j] << 16);
                    float by = __uint_as_float(bpA[j] & 0xffff0000u);
                    float m0 = fmaf(eav, u2.x, acxA) + bx;
                    float m1 = fmaf(eav, u2.y, acyA) + by;
                    sxA += m0; qxA = fmaf(m0, m0, qxA);
                    syA += m1; qyA = fmaf(m1, m1, qyA);
                    mnxA = fminf(mnxA, m0); mxxA = fmaxf(mxxA, m0);
                    mnyA = fminf(mnyA, m1); mxyA = fmaxf(mxyA, m1);
                }
            }
            #pragma unroll
            for (int j = 0; j < 4; j++) {
                int idx = i + 2 * j;
                if (idx < cntB) {
                    float eav = __int_as_float(sortd[loB + idx].y);
                    float bx = __uint_as_float(bpB[j] << 16);
                    float by = __uint_as_float(bpB[j] & 0xffff0000u);
                    float m0 = fmaf(eav, u2.x, acxB) + bx;
                    float m1 = fmaf(eav, u2.y, acyB) + by;
                    sxB += m0; qxB = fmaf(m0, m0, qxB);
                    syB += m1; qyB = fmaf(m1, m1, qyB);
                    mnxB = fminf(mnxB, m0); mxxB = fmaxf(mxxB, m0);
                    mnyB = fminf(mnyB, m1); mxyB = fmaxf(mxyB, m1);
                }
            }
        }

        auto finish = [&](int nl_, int cnt, float sx, float sy, float qx, float qy,
                          float mnx, float mny, float mxx, float mxy) {
            sx += __shfl_xor(sx, 32); sy += __shfl_xor(sy, 32);
            qx += __shfl_xor(qx, 32); qy += __shfl_xor(qy, 32);
            mnx = fminf(mnx, __shfl_xor(mnx, 32)); mny = fminf(mny, __shfl_xor(mny, 32));
            mxx = fmaxf(mxx, __shfl_xor(mxx, 32)); mxy = fmaxf(mxy, __shfl_xor(mxy, 32));
            float c1 = (cnt > 0) ? (float)cnt : 1.f;
            float inv = 1.f / c1;
            float mex = sx * inv, mey = sy * inv;
            float vx = qx * inv - mex * mex; if (vx < 0.f) vx = 0.f;
            float vy = qy * inv - mey * mey; if (vy < 0.f) vy = 0.f;
            float sdx = sqrtf(vx + 1e-5f), sdy = sqrtf(vy + 1e-5f);
            if (cnt == 0) { mnx = mny = mxx = mxy = 0.f; }
            if (hi32 == 0) {
                lstat[nl_][half]      = packbf2(mex, mey);
                lstat[nl_][32 + half] = packbf2(mnx, mny);
            } else {
                lstat[nl_][64 + half] = packbf2(mxx, mxy);
                lstat[nl_][96 + half] = packbf2(sdx, sdy);
            }
            if (lane == 0) {
                float amp = logf(c1 + 1.f) * AVG_LOG_INV;
                lamp[nl_] = amp; liamp[nl_] = 1.f / amp;
            }
        };
        finish(nlA, cntA, sxA, syA, qxA, qyA, mnxA, mnyA, mxxA, mxyA);
        if (hasB) finish(nlB, cntB, sxB, syB, qxB, qyB, mnxB, mnyB, mxxB, mxyB);
    }
    __syncthreads();

    // fused per-graph segment reduce, 193 parallel columns:
    //  t <128   : stats col t (stat=t>>5 in {mean,mn,mx,sd}; feats 2*(t&31),+1)
    //  t 128-191: x col t-128
    //  t ==192  : node count
    if (t < 128) {
        int c = t;
        int elem = ((c >> 5) << 6) + ((c & 31) << 1);
        float s1x = 0.f, s1y = 0.f, s2x = 0.f, s2y = 0.f, s3x = 0.f, s3y = 0.f;
        int cur = gid[0];
        for (int nl = 0; nl < nn; nl++) {
            int g = gid[nl];
            if (g != cur) {
                float* gf = gfeat + (size_t)cur * 832;
                unsafeAtomicAdd(&gf[64 + elem], s1x);
                unsafeAtomicAdd(&gf[65 + elem], s1y);
                unsafeAtomicAdd(&gf[320 + elem], s2x);
                unsafeAtomicAdd(&gf[321 + elem], s2y);
                unsafeAtomicAdd(&gf[576 + elem], s3x);
                unsafeAtomicAdd(&gf[577 + elem], s3y);
                s1x = s1y = s2x = s2y = s3x = s3y = 0.f;
                cur = g;
            }
            unsigned p = lstat[nl][c];
            float bx = __uint_as_float(p << 16);
            float by = __uint_as_float(p & 0xffff0000u);
            float a = lamp[nl], ia = liamp[nl];
            s1x += bx; s2x = fmaf(bx, a, s2x); s3x = fmaf(bx, ia, s3x);
            s1y += by; s2y = fmaf(by, a, s2y); s3y = fmaf(by, ia, s3y);
        }
        float* gf = gfeat + (size_t)cur * 832;
        unsafeAtomicAdd(&gf[64 + elem], s1x);
        unsafeAtomicAdd(&gf[65 + elem], s1y);
        unsafeAtomicAdd(&gf[320 + elem], s2x);
        unsafeAtomicAdd(&gf[321 + elem], s2y);
        unsafeAtomicAdd(&gf[576 + elem], s3x);
        unsafeAtomicAdd(&gf[577 + elem], s3y);
    } else if (t < 192) {
        int c = t - 128;
        float sxv = 0.f;
        int cur = gid[0];
        for (int nl = 0; nl < nn; nl++) {
            int g = gid[nl];
            if (g != cur) {
                unsafeAtomicAdd(&gfeat[(size_t)cur * 832 + c], sxv);
                sxv = 0.f; cur = g;
            }
            sxv += x[(size_t)(b * BNODES + nl) * 64 + c];
        }
        unsafeAtomicAdd(&gfeat[(size_t)cur * 832 + c], sxv);
    } else if (t == 192) {
        int cnt = 0, cur = gid[0];
        for (int nl = 0; nl < nn; nl++) {
            int g = gid[nl];
            if (g != cur) { atomicAdd(&gcnt[cur], cnt); cnt = 0; cur = g; }
            cnt++;
        }
        atomicAdd(&gcnt[cur], cnt);
    }
}

// Zin[g] = ((gfeat[g]/cnt) @ W_post + b_post) @ W_lin + b_lin ; 8-way split-k
__global__ __launch_bounds__(1024) void k_post1(
    const float* __restrict__ gfeat, const int* __restrict__ gcnt,
    const float* __restrict__ W_post, const float* __restrict__ b_post,
    const float* __restrict__ W_lin, const float* __restrict__ b_lin,
    float* __restrict__ Zin) {
    int g = blockIdx.x, t = threadIdx.x;  // 1024
    int j = t & 127, h = t >> 7;          // h = 0..7
    __shared__ float feat[832];
    __shared__ float part[1024];
    __shared__ float z1[128];
    int cg = gcnt[g];
    float r = 1.f / ((cg > 0) ? (float)cg : 1.f);
    for (int i = t; i < 832; i += 1024) feat[i] = gfeat[(size_t)g * 832 + i] * r;
    __syncthreads();
    float acc = (h == 0) ? b_post[j] : 0.f;
    const float* Wp = W_post + (size_t)(h * 104) * 128 + j;
    const float* fp = feat + h * 104;
    #pragma unroll 8
    for (int k = 0; k < 104; k++) acc += fp[k] * Wp[(size_t)k * 128];
    part[t] = acc;
    __syncthreads();
    if (t < 128) {
        float s = 0.f;
        #pragma unroll
        for (int hh = 0; hh < 8; hh++) s += part[hh * 128 + j];
        z1[j] = s;
    }
    __syncthreads();
    float a2 = (h == 0) ? b_lin[j] : 0.f;
    #pragma unroll
    for (int k = 0; k < 16; k++) a2 += z1[h * 16 + k] * W_lin[(h * 16 + k) * 128 + j];
    part[t] = a2;
    __syncthreads();
    if (t < 128) {
        float v = 0.f;
        #pragma unroll
        for (int hh = 0; hh < 8; hh++) v += part[hh * 128 + j];
        if (cg == 0) v = 0.f;
        Zin[g * 128 + j] = v;
    }
}

// column-parallel MLP layer: block j computes output column j of
//   out = relu( BN(in' @ W + bias; gamma,beta) [+ res] ), in' = relu(BN(in)) if g_in
__global__ void k_mlpcol(const float* __restrict__ in, const float* __restrict__ W,
                         const float* __restrict__ bias,
                         const float* __restrict__ gamma, const float* __restrict__ beta,
                         const float* __restrict__ res,
                         const float* __restrict__ g_in, const float* __restrict__ be_in,
                         float* __restrict__ outp) {
    __shared__ float A[64 * 129];
    __shared__ float part[4 * 64];
    int t = threadIdx.x;  // 256
    int j = blockIdx.x;   // 128

    for (int i = t; i < 8192; i += 256) A[(i >> 7) * 129 + (i & 127)] = in[i];
    __syncthreads();

    if (g_in) {
        if (t < 128) {
            int c = t;
            float mu = 0.f;
            for (int r = 0; r < 64; r++) mu += A[r * 129 + c];
            mu *= (1.f / 64.f);
            float var = 0.f;
            for (int r = 0; r < 64; r++) { float d = A[r * 129 + c] - mu; var += d * d; }
            var *= (1.f / 64.f);
            float sc = rsqrtf(var + 1e-5f) * g_in[c], sh = be_in[c];
            for (int r = 0; r < 64; r++) {
                float v = (A[r * 129 + c] - mu) * sc + sh;
                A[r * 129 + c] = v > 0.f ? v : 0.f;
            }
        }
        __syncthreads();
    }

    int r = t & 63, q = t >> 6;
    float acc = 0.f;
    int k0 = q * 32;
    #pragma unroll
    for (int k = 0; k < 32; k++) acc += A[r * 129 + k0 + k] * W[(k0 + k) * 128 + j];
    part[q * 64 + r] = acc;
    __syncthreads();

    if (t < 64) {
        float v = part[t] + part[64 + t] + part[128 + t] + part[192 + t] + bias[j];
        float mu = wave_sum(v) * (1.f / 64.f);
        float d = v - mu;
        float var = wave_sum(d * d) * (1.f / 64.f);
        float o = d * rsqrtf(var + 1e-5f) * gamma[j] + beta[j];
        if (res) o += res[t * 128 + j];
        outp[t * 128 + j] = o > 0.f ? o : 0.f;
    }
}

__global__ void k_out(const float* __restrict__ z4, const float* __restrict__ W_out,
                      const float* b_out, float* __restrict__ out) {
    int g = threadIdx.x;  // 64
    float acc = b_out[0];
    for (int j = 0; j < 128; j++) acc += z4[g * 128 + j] * W_out[j];
    out[g] = acc;
}

extern "C" void kernel_launch(void* const* d_in, const int* in_sizes, int n_in,
                              void* d_out, int out_size, void* d_ws, size_t ws_size,
                              hipStream_t stream) {
    const float* x      = (const float*)d_in[0];
    const int*   ei     = (const int*)d_in[1];
    const float* ea     = (const float*)d_in[2];
    const int*   batch  = (const int*)d_in[3];
    const float* W_edge = (const float*)d_in[4];
    const float* b_edge = (const float*)d_in[5];
    const float* W_pre  = (const float*)d_in[6];
    const float* b_pre  = (const float*)d_in[7];
    const float* W_post = (const float*)d_in[8];
    const float* b_post = (const float*)d_in[9];
    const float* W_lin  = (const float*)d_in[10];
    const float* b_lin  = (const float*)d_in[11];
    const float* g1     = (const float*)d_in[12];
    const float* be1    = (const float*)d_in[13];
    const float* W2     = (const float*)d_in[14];
    const float* b2     = (const float*)d_in[15];
    const float* g2     = (const float*)d_in[16];
    const float* be2    = (const float*)d_in[17];
    const float* Wr1    = (const float*)d_in[18];
    const float* br1    = (const float*)d_in[19];
    const float* gr1    = (const float*)d_in[20];
    const float* ber1   = (const float*)d_in[21];
    const float* Wr2    = (const float*)d_in[22];
    const float* br2    = (const float*)d_in[23];
    const float* gr2    = (const float*)d_in[24];
    const float* ber2   = (const float*)d_in[25];
    const float* W_out  = (const float*)d_in[26];
    const float* b_out  = (const float*)d_in[27];
    float* out = (float*)d_out;

    const int N = in_sizes[0] / F;      // 50000  (must be <= 65536 for record packing)
    const int E = in_sizes[1] / 2;      // 800000 (must be <= NBTMAX*BTILE)
    const int G = out_size;             // 64
    const int NB = (N + BNODES - 1) >> BSH;  // 3125 buckets

    char* p = (char*)d_ws;
    auto alloc = [&](size_t nbytes) { void* r = p; p += (nbytes + 255) & ~(size_t)255; return r; };
    const int NBT = (E + BTILE - 1) / BTILE;        // 25 partition blocks
    bf16*  AB     = (bf16*)alloc((size_t)N * 128 * sizeof(bf16));
    int2*  gout   = (int2*)alloc((size_t)NBT * BTILE * sizeof(int2));
    int*   ofs    = (int*)alloc((size_t)NBT * (NB + 1) * sizeof(int));
    float* uc     = (float*)alloc(128 * sizeof(float));
    float* gfeat  = (float*)alloc((size_t)G * 832 * sizeof(float));
    int*   gcnt   = (int*)alloc((size_t)G * sizeof(int));
    float* Zin    = (float*)alloc(64 * 128 * sizeof(float));
    float* z2b    = (float*)alloc(64 * 128 * sizeof(float));
    float* z3b    = (float*)alloc(64 * 128 * sizeof(float));
    float* z4b    = (float*)alloc(64 * 128 * sizeof(float));

    const int GF = G * 832;
    const int NAB = (((N + 15) >> 4) + 7) >> 3;     // AB blocks: 1 tile/wave, 8 waves/block

    k_prep<<<NBT + NAB, 512, 0, stream>>>(x, W_pre, AB, N, ei, ea, ofs, gout, E,
                                          gfeat, gcnt, NB, GF, G, NBT,
                                          W_edge, b_edge, b_pre, uc);
    k_edge<<<NB, 256, 0, stream>>>(AB, gout, ofs, uc, batch, x, gfeat, gcnt, N, NB, NBT);
    k_post1<<<G, 1024, 0, stream>>>(gfeat, gcnt, W_post, b_post, W_lin, b_lin, Zin);
    k_mlpcol<<<HG, 256, 0, stream>>>(Zin, W2, b2, g2, be2, nullptr, g1, be1, z2b);
    k_mlpcol<<<HL, 256, 0, stream>>>(z2b, Wr1, br1, gr1, ber1, nullptr, nullptr, nullptr, z3b);
    k_mlpcol<<<HL, 256, 0, stream>>>(z3b, Wr2, br2, gr2, ber2, z2b, nullptr, nullptr, z4b);
    k_out<<<1, 64, 0, stream>>>(z4b, W_out, b_out, out);
}

// Round 8
// 212.927 us; speedup vs baseline: 1.1055x; 1.1055x over previous
//
#include <hip/hip_runtime.h>
#include <hip/hip_bf16.h>

using bf16 = __hip_bfloat16;

#define F 64
#define HG 128
#define HL 128
#define AVG_LOG_INV 0.45511961331341866f  // 1/log(9)
#define BSH 4            // 16 nodes per bucket
#define BNODES 16
#define BCAP 512         // per-bucket record capacity (mean 256, +16 sigma)
#define BTILE 8192       // edges per partition block
#define NBMAX 3200       // LDS hist array size (>= NB)
#define NBTMAX 128       // max partition blocks (E <= 128*8192)

typedef short short8 __attribute__((ext_vector_type(8)));
typedef float floatx4 __attribute__((ext_vector_type(4)));

__device__ __forceinline__ float b2f(bf16 v) { return __bfloat162float(v); }
__device__ __forceinline__ bf16 f2b(float v) { return __float2bfloat16(v); }
__device__ __forceinline__ short f2bs(float v) { bf16 h = f2b(v); return *(short*)&h; }

__device__ __forceinline__ unsigned packbf2(float x, float y) {
    bf16 a = f2b(x), b = f2b(y);
    unsigned short ua = *(unsigned short*)&a, ub = *(unsigned short*)&b;
    return ((unsigned)ub << 16) | (unsigned)ua;
}

__device__ __forceinline__ float wave_sum(float v) {
    #pragma unroll
    for (int m = 32; m > 0; m >>= 1) v += __shfl_xor(v, m);
    return v;
}

// Fused: [init gfeat/gcnt/uc] + edge partition (blocks < NBT) + AB MFMA staging
// (blocks >= NBT). Partition is block-local CSR: block p sorts its BTILE edges
// by bucket into gout[p*BTILE..]. Offsets stored TRANSPOSED: ofs[b*NBT + p]
// (so k_edge block b reads one contiguous row; sentinel row at b=NB holds lim).
__global__ __launch_bounds__(512) void k_prep(
    const float* __restrict__ x, const float* __restrict__ W_pre,
    bf16* __restrict__ AB, int N,
    const int* __restrict__ ei, const float* __restrict__ ea,
    int* __restrict__ ofs, int2* __restrict__ gout, int E,
    float* __restrict__ gfeat, int* __restrict__ gcnt,
    int NB, int GF, int G, int NBT,
    const float* __restrict__ W_edge, const float* __restrict__ b_edge,
    const float* __restrict__ b_pre, float* __restrict__ uc) {
    __shared__ __align__(16) char smem[2 * NBMAX * 4];   // 25.6KB (>=18.4KB wt)
    int t = threadIdx.x;  // 512
    int gtid = blockIdx.x * 512 + t;
    int gstr = gridDim.x * 512;
    for (int i = gtid; i < GF; i += gstr) gfeat[i] = 0.f;
    for (int i = gtid; i < G; i += gstr) gcnt[i] = 0;

    if (blockIdx.x < NBT) {
        // ---------------- partition role ----------------
        int* hist = (int*)smem;          // NBMAX: counts -> exclusive offsets
        int* aux  = hist + NBMAX;        // NBMAX: scan temp -> rank counters
        int p = blockIdx.x;
        for (int i = t; i < NB; i += 512) hist[i] = 0;
        __syncthreads();
        int base = p * BTILE;
        int lim = E - base; if (lim > BTILE) lim = BTILE;
        int nq = lim >> 2;
        const int4* dst4 = (const int4*)(ei + E + base);
        for (int q = t; q < nq; q += 512) {
            int4 d = dst4[q];
            atomicAdd(&hist[d.x >> BSH], 1);
            atomicAdd(&hist[d.y >> BSH], 1);
            atomicAdd(&hist[d.z >> BSH], 1);
            atomicAdd(&hist[d.w >> BSH], 1);
        }
        for (int i = (nq << 2) + t; i < lim; i += 512)
            atomicAdd(&hist[ei[E + base + i] >> BSH], 1);
        __syncthreads();
        // exclusive scan over NB buckets: each thread owns 8 consecutive
        int b0 = t * 8;
        int c[8]; int tot = 0;
        #pragma unroll
        for (int j = 0; j < 8; j++) {
            c[j] = (b0 + j < NB) ? hist[b0 + j] : 0;
            tot += c[j];
        }
        aux[t] = tot;
        __syncthreads();
        for (int d = 1; d < 512; d <<= 1) {
            int v = (t >= d) ? aux[t - d] : 0;
            __syncthreads();
            aux[t] += v;
            __syncthreads();
        }
        int run = aux[t] - tot;  // exclusive prefix for this thread's group
        __syncthreads();
        #pragma unroll
        for (int j = 0; j < 8; j++) {
            if (b0 + j < NB) {
                hist[b0 + j] = run;
                ofs[(size_t)(b0 + j) * NBT + p] = run;   // transposed
                run += c[j];
            }
        }
        if (t == 0) ofs[(size_t)NB * NBT + p] = lim;     // sentinel row
        for (int i = t; i < NB; i += 512) aux[i] = 0;    // rank counters
        __syncthreads();
        // pass 2: re-read edges, scatter into block-local segment (64KB window)
        const int4* src4 = (const int4*)(ei + base);
        const float4* ea4 = (const float4*)(ea + base);
        int2* seg = gout + (size_t)p * BTILE;
        for (int q = t; q < nq; q += 512) {
            int4 s = src4[q], d = dst4[q];
            float4 v = ea4[q];
            int bb, pos;
            bb = d.x >> BSH; pos = hist[bb] + atomicAdd(&aux[bb], 1);
            seg[pos] = make_int2((d.x << 16) | s.x, __float_as_int(v.x));
            bb = d.y >> BSH; pos = hist[bb] + atomicAdd(&aux[bb], 1);
            seg[pos] = make_int2((d.y << 16) | s.y, __float_as_int(v.y));
            bb = d.z >> BSH; pos = hist[bb] + atomicAdd(&aux[bb], 1);
            seg[pos] = make_int2((d.z << 16) | s.z, __float_as_int(v.z));
            bb = d.w >> BSH; pos = hist[bb] + atomicAdd(&aux[bb], 1);
            seg[pos] = make_int2((d.w << 16) | s.w, __float_as_int(v.w));
        }
        for (int i = (nq << 2) + t; i < lim; i += 512) {
            int s = ei[base + i], d = ei[E + base + i];
            int bb = d >> BSH;
            int pos = hist[bb] + atomicAdd(&aux[bb], 1);
            seg[pos] = make_int2((d << 16) | s, __float_as_int(ea[base + i]));
        }
    } else {
        // ---------------- AB MFMA role ----------------
        if (blockIdx.x == NBT && t < 64) {
            int f = t;
            float u = 0.f, c2 = b_pre[f];
            for (int k = 0; k < 64; k++) {
                float w3 = W_pre[(128 + k) * 64 + f];
                u += W_edge[k] * w3;
                c2 += b_edge[k] * w3;
            }
            uc[f] = u; uc[64 + f] = c2;
        }
        unsigned short* wt = (unsigned short*)smem;  // wt[m][k], 128x72
        for (int idx = t; idx < 8192; idx += 512) {
            int k = idx >> 7, m = idx & 127;
            float v = W_pre[((m & 64) + k) * 64 + (m & 63)];
            wt[m * 72 + k] = (unsigned short)f2bs(v);
        }
        __syncthreads();

        int lane = t & 63;
        int row = lane & 15, quad = lane >> 4;
        int w = (blockIdx.x - NBT) * 8 + (t >> 6);
        int nwaves = (gridDim.x - NBT) * 8;
        int ntiles = (N + 15) >> 4;

        for (int tile = w; tile < ntiles; tile += nwaves) {
            int m0 = tile << 4;
            int node_a = m0 + row; if (node_a >= N) node_a = N - 1;
            short8 a[2];
            #pragma unroll
            for (int h = 0; h < 2; h++) {
                const float* xp = x + (size_t)node_a * 64 + h * 32 + quad * 8;
                floatx4 v0 = *(const floatx4*)xp;
                floatx4 v1 = *(const floatx4*)(xp + 4);
                #pragma unroll
                for (int j = 0; j < 4; j++) { a[h][j] = f2bs(v0[j]); a[h][4 + j] = f2bs(v1[j]); }
            }
            #pragma unroll
            for (int tt = 0; tt < 8; tt++) {
                int fbase = tt * 16;
                floatx4 c = {0.f, 0.f, 0.f, 0.f};
                #pragma unroll
                for (int h = 0; h < 2; h++) {
                    short8 bfr = *(const short8*)(wt + (fbase + row) * 72 + h * 32 + quad * 8);
                    c = __builtin_amdgcn_mfma_f32_16x16x32_bf16(a[h], bfr, c, 0, 0, 0);
                }
                #pragma unroll
                for (int r = 0; r < 4; r++) {
                    int node = m0 + quad * 4 + r;
                    if (node < N) AB[(size_t)node * 128 + fbase + row] = f2b(c[r]);
                }
            }
        }
    }
}

// one block (256 thr, 4 waves) per bucket (16 nodes). Setup: read two
// CONTIGUOUS transposed ofs rows (b and b+1), 64-lane shfl scan (2 runs/lane),
// binary-search CSR assembly, LDS counting-sort, dual-node LDS-broadcast
// gather, fused per-graph segment reduce (193 cols: 128 stats + 64 x + cnt).
__global__ __launch_bounds__(256) void k_edge(
    const bf16* __restrict__ AB, const int2* __restrict__ gout,
    const int* __restrict__ ofs, const float* __restrict__ uc,
    const int* __restrict__ batch, const float* __restrict__ x,
    float* __restrict__ gfeat, int* __restrict__ gcnt,
    int N, int NB, int NBT) {
    __shared__ int2 recs[BCAP], sortd[BCAP];
    __shared__ int ncnt[BNODES], nofs[BNODES], nrank[BNODES];
    __shared__ int gid[BNODES];
    __shared__ unsigned lstat[BNODES][128];   // packed bf16 pairs: [mean|mn|mx|sd]
    __shared__ float lamp[BNODES], liamp[BNODES];
    __shared__ int runlo[NBTMAX], runpre[NBTMAX];
    __shared__ int etot_s;
    int t = threadIdx.x;  // 256
    int b = blockIdx.x;
    int nn = N - b * BNODES; if (nn > BNODES) nn = BNODES;

    // ---- setup: wave 0 loads both ofs rows (coalesced) + 64-lane shfl scan
    if (t < 64) {
        int l = t;
        int p0 = 2 * l, p1 = 2 * l + 1;
        const int* rowA = ofs + (size_t)b * NBT;
        const int* rowB = ofs + (size_t)(b + 1) * NBT;
        int lo0 = 0, len0 = 0, lo1 = 0, len1 = 0;
        if (p0 < NBT) { lo0 = rowA[p0]; len0 = rowB[p0] - lo0; }
        if (p1 < NBT) { lo1 = rowA[p1]; len1 = rowB[p1] - lo1; }
        runlo[p0] = lo0; runlo[p1] = lo1;
        int s = len0 + len1, inc = s;
        #pragma unroll
        for (int m = 1; m < 64; m <<= 1) { int u = __shfl_up(inc, m); if (l >= m) inc += u; }
        int ex = inc - s;
        runpre[p0] = ex; runpre[p1] = ex + len0;
        if (l == 63) etot_s = inc;
    } else if (t < 64 + BNODES) {
        int i = t - 64;  // i < BNODES
        ncnt[i] = 0; nrank[i] = 0;
        if (i < nn) gid[i] = batch[b * BNODES + i];
    }
    __syncthreads();

    int ecnt = etot_s; if (ecnt > BCAP) ecnt = BCAP;
    for (int i = t; i < ecnt; i += 256) {
        int lo2 = 0, hi2 = NBTMAX;  // largest p with runpre[p] <= i
        while (hi2 - lo2 > 1) {
            int mid = (lo2 + hi2) >> 1;
            if (runpre[mid] <= i) lo2 = mid; else hi2 = mid;
        }
        int2 r = gout[(size_t)lo2 * BTILE + runlo[lo2] + (i - runpre[lo2])];
        recs[i] = r;
        atomicAdd(&ncnt[((unsigned)r.x >> 16) & (BNODES - 1)], 1);
    }
    __syncthreads();
    if (t < BNODES) {  // exclusive scan over node counts
        int v = ncnt[t], inc = v;
        #pragma unroll
        for (int m = 1; m < BNODES; m <<= 1) { int u = __shfl_up(inc, m); if (t >= m) inc += u; }
        nofs[t] = inc - v;
    }
    __syncthreads();
    for (int i = t; i < ecnt; i += 256) {
        int2 r = recs[i];
        int nl = ((unsigned)r.x >> 16) & (BNODES - 1);
        int k = atomicAdd(&nrank[nl], 1);
        sortd[nofs[nl] + k] = r;
    }
    __syncthreads();

    int lane = t & 63, w = t >> 6;  // 4 waves
    int half = lane & 31, hi32 = lane >> 5;
    float2 u2 = *(const float2*)(uc + 2 * half);
    float2 c2 = *(const float2*)(uc + 64 + 2 * half);

    // dual-node gather: wave w handles nodes (nl, nl+4) concurrently
    for (int nl = w; nl < nn; nl += 8) {
        int nlA = nl, nlB = nl + 4;
        bool hasB = (nlB < nn);
        int nA = b * BNODES + nlA;
        int nB = b * BNODES + (hasB ? nlB : nlA);
        int loA = nofs[nlA], cntA = ncnt[nlA];
        int loB = hasB ? nofs[nlB] : 0, cntB = hasB ? ncnt[nlB] : 0;

        unsigned apA = *(const unsigned*)(AB + (size_t)nA * 128 + 2 * half);
        unsigned apB = *(const unsigned*)(AB + (size_t)nB * 128 + 2 * half);
        float acxA = __uint_as_float(apA << 16) + c2.x;
        float acyA = __uint_as_float(apA & 0xffff0000u) + c2.y;
        float acxB = __uint_as_float(apB << 16) + c2.x;
        float acyB = __uint_as_float(apB & 0xffff0000u) + c2.y;

        float sxA = 0.f, syA = 0.f, qxA = 0.f, qyA = 0.f;
        float mnxA = 3.4e38f, mnyA = 3.4e38f, mxxA = -3.4e38f, mxyA = -3.4e38f;
        float sxB = 0.f, syB = 0.f, qxB = 0.f, qyB = 0.f;
        float mnxB = 3.4e38f, mnyB = 3.4e38f, mxxB = -3.4e38f, mxyB = -3.4e38f;

        auto gaddr = [&](int sn) {
            return (const unsigned*)(AB + (size_t)sn * 128 + 64 + 2 * half);
        };

        // hi32=0 lanes take even edge indices, hi32=1 odd
        for (int i = hi32; (i < cntA) || (i < cntB); i += 8) {
            unsigned bpA[4], bpB[4];
            #pragma unroll
            for (int j = 0; j < 4; j++) {
                int idx = i + 2 * j;
                int e = loA + (idx < cntA ? idx : 0);
                bpA[j] = *gaddr(sortd[e].x & 0xFFFF);   // LDS broadcast -> gather
            }
            #pragma unroll
            for (int j = 0; j < 4; j++) {
                int idx = i + 2 * j;
                int e = loB + (idx < cntB ? idx : 0);
                bpB[j] = *gaddr(sortd[e].x & 0xFFFF);
            }
            #pragma unroll
            for (int j = 0; j < 4; j++) {
                int idx = i + 2 * j;
                if (idx < cntA) {
                    float eav = __int_as_float(sortd[loA + idx].y);
                    float bx = __uint_as_float(bpA[j] << 16);
                    float by = __uint_as_float(bpA[j] & 0xffff0000u);
                    float m0 = fmaf(eav, u2.x, acxA) + bx;
                    float m1 = fmaf(eav, u2.y, acyA) + by;
                    sxA += m0; qxA = fmaf(m0, m0, qxA);
                    syA += m1; qyA = fmaf(m1, m1, qyA);
                    mnxA = fminf(mnxA, m0); mxxA = fmaxf(mxxA, m0);
                    mnyA = fminf(mnyA, m1); mxyA = fmaxf(mxyA, m1);
                }
            }
            #pragma unroll
            for (int j = 0; j < 4; j++) {
                int idx = i + 2 * j;
                if (idx < cntB) {
                    float eav = __int_as_float(sortd[loB + idx].y);
                    float bx = __uint_as_float(bpB[j] << 16);
                    float by = __uint_as_float(bpB[j] & 0xffff0000u);
                    float m0 = fmaf(eav, u2.x, acxB) + bx;
                    float m1 = fmaf(eav, u2.y, acyB) + by;
                    sxB += m0; qxB = fmaf(m0, m0, qxB);
                    syB += m1; qyB = fmaf(m1, m1, qyB);
                    mnxB = fminf(mnxB, m0); mxxB = fmaxf(mxxB, m0);
                    mnyB = fminf(mnyB, m1); mxyB = fmaxf(mxyB, m1);
                }
            }
        }

        auto finish = [&](int nl_, int cnt, float sx, float sy, float qx, float qy,
                          float mnx, float mny, float mxx, float mxy) {
            sx += __shfl_xor(sx, 32); sy += __shfl_xor(sy, 32);
            qx += __shfl_xor(qx, 32); qy += __shfl_xor(qy, 32);
            mnx = fminf(mnx, __shfl_xor(mnx, 32)); mny = fminf(mny, __shfl_xor(mny, 32));
            mxx = fmaxf(mxx, __shfl_xor(mxx, 32)); mxy = fmaxf(mxy, __shfl_xor(mxy, 32));
            float c1 = (cnt > 0) ? (float)cnt : 1.f;
            float inv = 1.f / c1;
            float mex = sx * inv, mey = sy * inv;
            float vx = qx * inv - mex * mex; if (vx < 0.f) vx = 0.f;
            float vy = qy * inv - mey * mey; if (vy < 0.f) vy = 0.f;
            float sdx = sqrtf(vx + 1e-5f), sdy = sqrtf(vy + 1e-5f);
            if (cnt == 0) { mnx = mny = mxx = mxy = 0.f; }
            if (hi32 == 0) {
                lstat[nl_][half]      = packbf2(mex, mey);
                lstat[nl_][32 + half] = packbf2(mnx, mny);
            } else {
                lstat[nl_][64 + half] = packbf2(mxx, mxy);
                lstat[nl_][96 + half] = packbf2(sdx, sdy);
            }
            if (lane == 0) {
                float amp = logf(c1 + 1.f) * AVG_LOG_INV;
                lamp[nl_] = amp; liamp[nl_] = 1.f / amp;
            }
        };
        finish(nlA, cntA, sxA, syA, qxA, qyA, mnxA, mnyA, mxxA, mxyA);
        if (hasB) finish(nlB, cntB, sxB, syB, qxB, qyB, mnxB, mnyB, mxxB, mxyB);
    }
    __syncthreads();

    // fused per-graph segment reduce, 193 parallel columns:
    //  t <128   : stats col t (stat=t>>5 in {mean,mn,mx,sd}; feats 2*(t&31),+1)
    //  t 128-191: x col t-128
    //  t ==192  : node count
    if (t < 128) {
        int c = t;
        int elem = ((c >> 5) << 6) + ((c & 31) << 1);
        float s1x = 0.f, s1y = 0.f, s2x = 0.f, s2y = 0.f, s3x = 0.f, s3y = 0.f;
        int cur = gid[0];
        for (int nl = 0; nl < nn; nl++) {
            int g = gid[nl];
            if (g != cur) {
                float* gf = gfeat + (size_t)cur * 832;
                unsafeAtomicAdd(&gf[64 + elem], s1x);
                unsafeAtomicAdd(&gf[65 + elem], s1y);
                unsafeAtomicAdd(&gf[320 + elem], s2x);
                unsafeAtomicAdd(&gf[321 + elem], s2y);
                unsafeAtomicAdd(&gf[576 + elem], s3x);
                unsafeAtomicAdd(&gf[577 + elem], s3y);
                s1x = s1y = s2x = s2y = s3x = s3y = 0.f;
                cur = g;
            }
            unsigned p = lstat[nl][c];
            float bx = __uint_as_float(p << 16);
            float by = __uint_as_float(p & 0xffff0000u);
            float a = lamp[nl], ia = liamp[nl];
            s1x += bx; s2x = fmaf(bx, a, s2x); s3x = fmaf(bx, ia, s3x);
            s1y += by; s2y = fmaf(by, a, s2y); s3y = fmaf(by, ia, s3y);
        }
        float* gf = gfeat + (size_t)cur * 832;
        unsafeAtomicAdd(&gf[64 + elem], s1x);
        unsafeAtomicAdd(&gf[65 + elem], s1y);
        unsafeAtomicAdd(&gf[320 + elem], s2x);
        unsafeAtomicAdd(&gf[321 + elem], s2y);
        unsafeAtomicAdd(&gf[576 + elem], s3x);
        unsafeAtomicAdd(&gf[577 + elem], s3y);
    } else if (t < 192) {
        int c = t - 128;
        float sxv = 0.f;
        int cur = gid[0];
        for (int nl = 0; nl < nn; nl++) {
            int g = gid[nl];
            if (g != cur) {
                unsafeAtomicAdd(&gfeat[(size_t)cur * 832 + c], sxv);
                sxv = 0.f; cur = g;
            }
            sxv += x[(size_t)(b * BNODES + nl) * 64 + c];
        }
        unsafeAtomicAdd(&gfeat[(size_t)cur * 832 + c], sxv);
    } else if (t == 192) {
        int cnt = 0, cur = gid[0];
        for (int nl = 0; nl < nn; nl++) {
            int g = gid[nl];
            if (g != cur) { atomicAdd(&gcnt[cur], cnt); cnt = 0; cur = g; }
            cnt++;
        }
        atomicAdd(&gcnt[cur], cnt);
    }
}

// Zin[g] = ((gfeat[g]/cnt) @ W_post + b_post) @ W_lin + b_lin ; 8-way split-k
__global__ __launch_bounds__(1024) void k_post1(
    const float* __restrict__ gfeat, const int* __restrict__ gcnt,
    const float* __restrict__ W_post, const float* __restrict__ b_post,
    const float* __restrict__ W_lin, const float* __restrict__ b_lin,
    float* __restrict__ Zin) {
    int g = blockIdx.x, t = threadIdx.x;  // 1024
    int j = t & 127, h = t >> 7;          // h = 0..7
    __shared__ float feat[832];
    __shared__ float part[1024];
    __shared__ float z1[128];
    int cg = gcnt[g];
    float r = 1.f / ((cg > 0) ? (float)cg : 1.f);
    for (int i = t; i < 832; i += 1024) feat[i] = gfeat[(size_t)g * 832 + i] * r;
    __syncthreads();
    float acc = (h == 0) ? b_post[j] : 0.f;
    const float* Wp = W_post + (size_t)(h * 104) * 128 + j;
    const float* fp = feat + h * 104;
    #pragma unroll 8
    for (int k = 0; k < 104; k++) acc += fp[k] * Wp[(size_t)k * 128];
    part[t] = acc;
    __syncthreads();
    if (t < 128) {
        float s = 0.f;
        #pragma unroll
        for (int hh = 0; hh < 8; hh++) s += part[hh * 128 + j];
        z1[j] = s;
    }
    __syncthreads();
    float a2 = (h == 0) ? b_lin[j] : 0.f;
    #pragma unroll
    for (int k = 0; k < 16; k++) a2 += z1[h * 16 + k] * W_lin[(h * 16 + k) * 128 + j];
    part[t] = a2;
    __syncthreads();
    if (t < 128) {
        float v = 0.f;
        #pragma unroll
        for (int hh = 0; hh < 8; hh++) v += part[hh * 128 + j];
        if (cg == 0) v = 0.f;
        Zin[g * 128 + j] = v;
    }
}

// column-parallel MLP layer: block j computes output column j of
//   out = relu( BN(in' @ W + bias; gamma,beta) [+ res] ), in' = relu(BN(in)) if g_in
__global__ void k_mlpcol(const float* __restrict__ in, const float* __restrict__ W,
                         const float* __restrict__ bias,
                         const float* __restrict__ gamma, const float* __restrict__ beta,
                         const float* __restrict__ res,
                         const float* __restrict__ g_in, const float* __restrict__ be_in,
                         float* __restrict__ outp) {
    __shared__ float A[64 * 129];
    __shared__ float part[4 * 64];
    int t = threadIdx.x;  // 256
    int j = blockIdx.x;   // 128

    for (int i = t; i < 8192; i += 256) A[(i >> 7) * 129 + (i & 127)] = in[i];
    __syncthreads();

    if (g_in) {
        if (t < 128) {
            int c = t;
            float mu = 0.f;
            for (int r = 0; r < 64; r++) mu += A[r * 129 + c];
            mu *= (1.f / 64.f);
            float var = 0.f;
            for (int r = 0; r < 64; r++) { float d = A[r * 129 + c] - mu; var += d * d; }
            var *= (1.f / 64.f);
            float sc = rsqrtf(var + 1e-5f) * g_in[c], sh = be_in[c];
            for (int r = 0; r < 64; r++) {
                float v = (A[r * 129 + c] - mu) * sc + sh;
                A[r * 129 + c] = v > 0.f ? v : 0.f;
            }
        }
        __syncthreads();
    }

    int r = t & 63, q = t >> 6;
    float acc = 0.f;
    int k0 = q * 32;
    #pragma unroll
    for (int k = 0; k < 32; k++) acc += A[r * 129 + k0 + k] * W[(k0 + k) * 128 + j];
    part[q * 64 + r] = acc;
    __syncthreads();

    if (t < 64) {
        float v = part[t] + part[64 + t] + part[128 + t] + part[192 + t] + bias[j];
        float mu = wave_sum(v) * (1.f / 64.f);
        float d = v - mu;
        float var = wave_sum(d * d) * (1.f / 64.f);
        float o = d * rsqrtf(var + 1e-5f) * gamma[j] + beta[j];
        if (res) o += res[t * 128 + j];
        outp[t * 128 + j] = o > 0.f ? o : 0.f;
    }
}

__global__ void k_out(const float* __restrict__ z4, const float* __restrict__ W_out,
                      const float* b_out, float* __restrict__ out) {
    int g = threadIdx.x;  // 64
    float acc = b_out[0];
    for (int j = 0; j < 128; j++) acc += z4[g * 128 + j] * W_out[j];
    out[g] = acc;
}

extern "C" void kernel_launch(void* const* d_in, const int* in_sizes, int n_in,
                              void* d_out, int out_size, void* d_ws, size_t ws_size,
                              hipStream_t stream) {
    const float* x      = (const float*)d_in[0];
    const int*   ei     = (const int*)d_in[1];
    const float* ea     = (const float*)d_in[2];
    const int*   batch  = (const int*)d_in[3];
    const float* W_edge = (const float*)d_in[4];
    const float* b_edge = (const float*)d_in[5];
    const float* W_pre  = (const float*)d_in[6];
    const float* b_pre  = (const float*)d_in[7];
    const float* W_post = (const float*)d_in[8];
    const float* b_post = (const float*)d_in[9];
    const float* W_lin  = (const float*)d_in[10];
    const float* b_lin  = (const float*)d_in[11];
    const float* g1     = (const float*)d_in[12];
    const float* be1    = (const float*)d_in[13];
    const float* W2     = (const float*)d_in[14];
    const float* b2     = (const float*)d_in[15];
    const float* g2     = (const float*)d_in[16];
    const float* be2    = (const float*)d_in[17];
    const float* Wr1    = (const float*)d_in[18];
    const float* br1    = (const float*)d_in[19];
    const float* gr1    = (const float*)d_in[20];
    const float* ber1   = (const float*)d_in[21];
    const float* Wr2    = (const float*)d_in[22];
    const float* br2    = (const float*)d_in[23];
    const float* gr2    = (const float*)d_in[24];
    const float* ber2   = (const float*)d_in[25];
    const float* W_out  = (const float*)d_in[26];
    const float* b_out  = (const float*)d_in[27];
    float* out = (float*)d_out;

    const int N = in_sizes[0] / F;      // 50000  (must be <= 65536 for record packing)
    const int E = in_sizes[1] / 2;      // 800000 (must be <= NBTMAX*BTILE)
    const int G = out_size;             // 64
    const int NB = (N + BNODES - 1) >> BSH;  // 3125 buckets

    char* p = (char*)d_ws;
    auto alloc = [&](size_t nbytes) { void* r = p; p += (nbytes + 255) & ~(size_t)255; return r; };
    const int NBT = (E + BTILE - 1) / BTILE;        // 98 partition blocks
    bf16*  AB     = (bf16*)alloc((size_t)N * 128 * sizeof(bf16));
    int2*  gout   = (int2*)alloc((size_t)NBT * BTILE * sizeof(int2));
    int*   ofs    = (int*)alloc((size_t)(NB + 1) * NBT * sizeof(int));
    float* uc     = (float*)alloc(128 * sizeof(float));
    float* gfeat  = (float*)alloc((size_t)G * 832 * sizeof(float));
    int*   gcnt   = (int*)alloc((size_t)G * sizeof(int));
    float* Zin    = (float*)alloc(64 * 128 * sizeof(float));
    float* z2b    = (float*)alloc(64 * 128 * sizeof(float));
    float* z3b    = (float*)alloc(64 * 128 * sizeof(float));
    float* z4b    = (float*)alloc(64 * 128 * sizeof(float));

    const int GF = G * 832;
    const int NAB = (((N + 15) >> 4) + 7) >> 3;     // AB blocks: 1 tile/wave, 8 waves/block

    k_prep<<<NBT + NAB, 512, 0, stream>>>(x, W_pre, AB, N, ei, ea, ofs, gout, E,
                                          gfeat, gcnt, NB, GF, G, NBT,
                                          W_edge, b_edge, b_pre, uc);
    k_edge<<<NB, 256, 0, stream>>>(AB, gout, ofs, uc, batch, x, gfeat, gcnt, N, NB, NBT);
    k_post1<<<G, 1024, 0, stream>>>(gfeat, gcnt, W_post, b_post, W_lin, b_lin, Zin);
    k_mlpcol<<<HG, 256, 0, stream>>>(Zin, W2, b2, g2, be2, nullptr, g1, be1, z2b);
    k_mlpcol<<<HL, 256, 0, stream>>>(z2b, Wr1, br1, gr1, ber1, nullptr, nullptr, nullptr, z3b);
    k_mlpcol<<<HL, 256, 0, stream>>>(z3b, Wr2, br2, gr2, ber2, z2b, nullptr, nullptr, z4b);
    k_out<<<1, 64, 0, stream>>>(z4b, W_out, b_out, out);
}